// Round 9
// baseline (483.436 us; speedup 1.0000x reference)
//
#include <hip/hip_runtime.h>
#include <hip/hip_bf16.h>

// B=4, S=2048, D=1024, P=1024 causal self-attention, bf16 MFMA pipeline.
// Round 16: merge scores+PV into one launch with device-scope flag handoff.
//  - R15 A/B calibrated marginal launch cost ~5us and showed a large
//    serialization cost between dependent dispatches; scores->PV only
//    actually depends per row-panel t on the t+1 scores tiles of panel t.
//  - tail_kernel: 544 scores blocks + 512 PV blocks in one grid. Scores
//    release: syncthreads (drain to L2) -> tid0 threadfence (L2 writeback)
//    -> atomicAdd(flags[z][t]). PV acquire: tid0 spin until flag==t+1 ->
//    barrier -> all-thread threadfence (invalidate) -> stage P.
//  - Liveness independent of dispatch order: __launch_bounds__(256,3) +
//    48KB LDS -> 3 blocks/CU = 768 slots > 512 PV blocks -> >=256 scores
//    blocks always resident -> progress (G16-safe).
//  - 4 -> 3 launches: prep(+L/flag zero), QKV, tail(scores+PV).
//  - GEMM core: 32x32x16 MFMA, 2-barrier structure, chunk-XOR LDS swizzle.

#define BDIM 4
#define SDIM 2048
#define DDIM 1024
#define PDIM 1024

typedef __attribute__((ext_vector_type(8))) short bf16x8;
typedef __attribute__((ext_vector_type(4))) float f32x4;
typedef __attribute__((ext_vector_type(16))) float f32x16;

// ---------- helpers ----------
__device__ __forceinline__ unsigned short f2bf(float f) {
    union { float f; unsigned int u; } v; v.f = f;
    unsigned int u = v.u;
    unsigned int r = (u + 0x7fffu + ((u >> 16) & 1u)) >> 16;
    return (unsigned short)r;
}

__device__ __forceinline__ float bf2f(unsigned short h) {
    union { unsigned int u; float f; } v;
    v.u = ((unsigned int)h) << 16;
    return v.f;
}

__device__ __forceinline__ void async16(const unsigned short* g, unsigned short* l) {
    __builtin_amdgcn_global_load_lds(
        (const __attribute__((address_space(1))) unsigned int*)g,
        (__attribute__((address_space(3))) unsigned int*)l,
        16, 0, 0);
}

// ---------- fused prep: cast x + transpose/cast W + zero L/flags ----------
__global__ __launch_bounds__(256) void prep_kernel(const float* __restrict__ x,
                                                   const float* __restrict__ W0,
                                                   const float* __restrict__ W1,
                                                   const float* __restrict__ W2,
                                                   unsigned short* __restrict__ Xb,
                                                   unsigned short* __restrict__ WT,
                                                   float* __restrict__ Lrow,
                                                   unsigned int* __restrict__ flags) {
    int bid = blockIdx.x;
    if (bid < 4096) {
        size_t i = (size_t)bid * 256 + threadIdx.x;
        float4 a = ((const float4*)x)[2 * i];
        float4 b = ((const float4*)x)[2 * i + 1];
        bf16x8 o;
        o[0] = (short)f2bf(a.x); o[1] = (short)f2bf(a.y);
        o[2] = (short)f2bf(a.z); o[3] = (short)f2bf(a.w);
        o[4] = (short)f2bf(b.x); o[5] = (short)f2bf(b.y);
        o[6] = (short)f2bf(b.z); o[7] = (short)f2bf(b.w);
        ((bf16x8*)Xb)[i] = o;
    } else if (bid < 4864) {
        int idx = bid - 4096;
        int wz = idx >> 8;   // 0..2
        int t  = idx & 255;
        const float* W = (wz == 0) ? W0 : (wz == 1) ? W1 : W2;
        unsigned short* Tz = WT + (size_t)wz * DDIM * PDIM;
        __shared__ float tle[64 * 65];  // pitch 65: transpose-read is 2-way (free)
        int r0 = (t >> 4) * 64, c0 = (t & 15) * 64;
#pragma unroll
        for (int kk = 0; kk < 4; kk++) {
            int it = (int)threadIdx.x + 256 * kk;
            int r = it >> 4, c4 = (it & 15) * 4;
            float4 v = *(const float4*)(W + (size_t)(r0 + r) * PDIM + c0 + c4);
            float* dst = tle + r * 65 + c4;
            dst[0] = v.x; dst[1] = v.y; dst[2] = v.z; dst[3] = v.w;
        }
        __syncthreads();
#pragma unroll
        for (int kk = 0; kk < 2; kk++) {
            int it = (int)threadIdx.x + 256 * kk;
            int c = it >> 3, ch = (it & 7) * 8;
            bf16x8 o;
#pragma unroll
            for (int j = 0; j < 8; j++)
                o[j] = (short)f2bf(tle[(ch + j) * 65 + c]);
            *(bf16x8*)(Tz + (size_t)(c0 + c) * DDIM + r0 + ch) = o;
        }
    } else {
        // zero Lrow (8192 f32) + flags (64 u32)
        float4 z4 = make_float4(0.f, 0.f, 0.f, 0.f);
#pragma unroll
        for (int kk = 0; kk < 8; kk++)
            ((float4*)Lrow)[(size_t)kk * 256 + threadIdx.x] = z4;
        if (threadIdx.x < 64) flags[threadIdx.x] = 0;
    }
}

// ---------- shared GEMM core: 128x128 tile, BK=64, 32x32x16 MFMA ----------
// XOR-swizzled LDS (stored chunk c of row r holds logical chunk c^(r&7)).
// A: ping-pong 2x16 KB; B: single 16 KB buffer (48 KB total).
// Frag addr: row = wbase + mi*32 + (lane&31); chunk = (ks*2 + lane>>5) ^ (lane&7).
template <int LDA, int LDB>
__device__ __forceinline__ void run_core(
    const unsigned short* __restrict__ A,
    const unsigned short* __restrict__ Bt,
    unsigned short* smem, int tm, int tn, int ns,
    f32x16 (&acc)[2][2]) {
    const int BK = 64;
    const int ABUF = 128 * BK;
    unsigned short* BsBuf = smem + 2 * ABUF;
    int tid  = threadIdx.x;
    int lane = tid & 63;
    int wave = tid >> 6;
    int wr   = (wave >> 1) * 64;
    int wc   = (wave & 1) * 64;
    int l31  = lane & 31;
    int hi   = lane >> 5;
    int rsw  = lane & 7;

    int srow = tid >> 3;
    int scol = ((tid & 7) ^ (srow & 7)) * 8;
    const unsigned short* Ag = A + (size_t)(tm + srow) * LDA + scol;
    const unsigned short* Bg = Bt + (size_t)(tn + srow) * LDB + scol;

    auto issueA = [&](int k0, int buf) {
        unsigned short* la = smem + buf * ABUF + tid * 8;
        async16(Ag + k0, la);
        async16(Ag + k0 + 32 * LDA, la + 2048);
        async16(Ag + k0 + 64 * LDA, la + 4096);
        async16(Ag + k0 + 96 * LDA, la + 6144);
    };
    auto issueB = [&](int k0) {
        unsigned short* lb = BsBuf + tid * 8;
        async16(Bg + k0, lb);
        async16(Bg + k0 + 32 * LDB, lb + 2048);
        async16(Bg + k0 + 64 * LDB, lb + 4096);
        async16(Bg + k0 + 96 * LDB, lb + 6144);
    };

    issueA(0, 0);
    issueB(0);
    for (int i = 0; i < ns; i++) {
        __syncthreads();  // sync1: drains A[i&1] + B
        bf16x8 bf[2][4];
#pragma unroll
        for (int nj = 0; nj < 2; nj++)
#pragma unroll
            for (int ks = 0; ks < 4; ks++)
                bf[nj][ks] = *(const bf16x8*)(BsBuf + (wc + nj * 32 + l31) * BK
                                                    + ((ks * 2 + hi) ^ rsw) * 8);
        __syncthreads();  // sync2: B buffer free
        if (i + 1 < ns) { issueA((i + 1) * BK, (i + 1) & 1); issueB((i + 1) * BK); }
        const unsigned short* As = smem + (i & 1) * ABUF;
#pragma unroll
        for (int mi = 0; mi < 2; mi++) {
            bf16x8 af[4];
#pragma unroll
            for (int ks = 0; ks < 4; ks++)
                af[ks] = *(const bf16x8*)(As + (wr + mi * 32 + l31) * BK
                                             + ((ks * 2 + hi) ^ rsw) * 8);
#pragma unroll
            for (int ks = 0; ks < 4; ks++)
#pragma unroll
                for (int nj = 0; nj < 2; nj++)
                    acc[mi][nj] = __builtin_amdgcn_mfma_f32_32x32x16_bf16(
                        af[ks], bf[nj][ks], acc[mi][nj], 0, 0, 0);
        }
    }
}

// ---------- QKV GEMM (MODE 0 of the old gemm_bt) ----------
// tn<1024 -> Q, <2048 -> Kb, else VT (transposed via LDS slabs).
__global__ __launch_bounds__(256) void qkv_kernel(
    const unsigned short* __restrict__ Xb, const unsigned short* __restrict__ WT,
    unsigned short* __restrict__ Q, unsigned short* __restrict__ Kb,
    unsigned short* __restrict__ VT) {
    const int ABUF = 128 * 64;
    __shared__ __attribute__((aligned(16))) unsigned short smem[2 * ABUF + 128 * 64];
    int tm = blockIdx.y * 128;
    int tn = blockIdx.x * 128;
    int tid  = threadIdx.x;
    int lane = tid & 63;
    int wave = tid >> 6;
    int wr   = (wave >> 1) * 64;
    int wc   = (wave & 1) * 64;
    int l31  = lane & 31;
    int hi   = lane >> 5;

    f32x16 acc[2][2] = {};
    run_core<DDIM, DDIM>(Xb, WT, smem, tm, tn, DDIM / 64, acc);

    if (tn < 2048) {
        unsigned short* D = (tn < 1024) ? Q : Kb;
        int cbase = tn & 1023;
#pragma unroll
        for (int mi = 0; mi < 2; mi++) {
#pragma unroll
            for (int nj = 0; nj < 2; nj++) {
                int c = cbase + wc + nj * 32 + l31;
#pragma unroll
                for (int g = 0; g < 4; g++) {
                    int r0 = tm + wr + mi * 32 + g * 8 + hi * 4;
#pragma unroll
                    for (int rr = 0; rr < 4; rr++)
                        D[(size_t)(r0 + rr) * 1024 + c] = f2bf(acc[mi][nj][g * 4 + rr]);
                }
            }
        }
    } else {
        // V region: transposed write via LDS (4 passes of 32 p-columns)
        int b = tm >> 11;
        int s0 = tm & 2047;
        unsigned short* VTb = VT + (size_t)b * (PDIM * SDIM)
                                 + (size_t)(tn - 2048) * SDIM + s0;
        const int TP = 136;
        unsigned short* T = smem;
        __syncthreads();
#pragma unroll
        for (int p = 0; p < 4; p++) {
            if ((wave & 1) == (p >> 1)) {
                int nj = p & 1;
#pragma unroll
                for (int mi = 0; mi < 2; mi++) {
#pragma unroll
                    for (int g = 0; g < 4; g++) {
                        int rl = wr + mi * 32 + g * 8 + hi * 4;
                        ushort4 w;
                        w.x = f2bf(acc[mi][nj][g * 4 + 0]);
                        w.y = f2bf(acc[mi][nj][g * 4 + 1]);
                        w.z = f2bf(acc[mi][nj][g * 4 + 2]);
                        w.w = f2bf(acc[mi][nj][g * 4 + 3]);
                        *(ushort4*)(T + l31 * TP + rl) = w;
                    }
                }
            }
            __syncthreads();
            {
                int lr = tid >> 3;
                int ck = (tid & 7) * 16;
                bf16x8 u0 = *(const bf16x8*)(T + lr * TP + ck);
                bf16x8 u1 = *(const bf16x8*)(T + lr * TP + ck + 8);
                unsigned short* dst = VTb + (size_t)(32 * p + lr) * SDIM + ck;
                *(bf16x8*)(dst) = u0;
                *(bf16x8*)(dst + 8) = u1;
            }
            __syncthreads();
        }
    }
}

// ---------- fused tail: scores (P0=exp(s-8), L sums) + PV (out = P0@VT^T / L) ----------
// blockIdx.x < 136: scores tile (packed lower triangle); else PV tile.
// Handoff per (z, row-panel t): flags[z*16+t] counts completed scores tiles;
// PV spins until == t+1. 3 blocks/CU co-residency (768 slots) > 512 PV
// blocks -> >=256 scores blocks always resident -> progress any order.
__global__ __launch_bounds__(256, 3) void tail_kernel(
    const unsigned short* __restrict__ Q, const unsigned short* __restrict__ Kb,
    unsigned short* __restrict__ P01, unsigned short* __restrict__ P23,
    const unsigned short* __restrict__ VT, float* __restrict__ out,
    float* __restrict__ Lrow, unsigned int* __restrict__ flags, float alpha) {
    const int ABUF = 128 * 64;
    __shared__ __attribute__((aligned(16))) unsigned short smem[2 * ABUF + 128 * 64];
    const long long sQ = (long long)SDIM * PDIM;
    const long long SS = (long long)SDIM * SDIM;
    int z = blockIdx.z;
    int tid  = threadIdx.x;
    int lane = tid & 63;
    int wave = tid >> 6;
    int wr   = (wave >> 1) * 64;
    int wc   = (wave & 1) * 64;
    int l31  = lane & 31;
    int hi   = lane >> 5;

    if (blockIdx.x < 136) {
        // ---- scores role ----
        int i = blockIdx.x;
        int t = (int)((sqrtf(8.f * i + 1.f) - 1.f) * 0.5f);
        if ((t + 1) * (t + 2) / 2 <= i) t++;
        if (t * (t + 1) / 2 > i) t--;
        int tm = t * 128;
        int tn = (i - t * (t + 1) / 2) * 128;

        const unsigned short* A  = Q + (long long)z * sQ;
        const unsigned short* Bt = Kb + (long long)z * sQ;
        unsigned short* P = (z < 2 ? P01 : P23) + (long long)(z & 1) * SS;

        f32x16 acc[2][2] = {};
        run_core<PDIM, PDIM>(A, Bt, smem, tm, tn, PDIM / 64, acc);

        float* Lb = Lrow + (size_t)z * SDIM;
#pragma unroll
        for (int mi = 0; mi < 2; mi++) {
#pragma unroll
            for (int g = 0; g < 4; g++) {
#pragma unroll
                for (int rr = 0; rr < 4; rr++) {
                    int r = tm + wr + mi * 32 + g * 8 + hi * 4 + rr;
                    float psum = 0.f;
#pragma unroll
                    for (int nj = 0; nj < 2; nj++) {
                        int c = tn + wc + nj * 32 + l31;
                        float p = 0.f;
                        if (c <= r)
                            p = __expf(acc[mi][nj][g * 4 + rr] * alpha - 8.0f);
                        psum += p;
                        P[(size_t)r * SDIM + c] = f2bf(p);
                    }
#pragma unroll
                    for (int o = 16; o; o >>= 1) psum += __shfl_xor(psum, o, 64);
                    if (l31 == 0) atomicAdd(Lb + r, psum);
                }
            }
        }
        __syncthreads();  // all stores/atomics drained to L2 (barrier implies vmcnt(0))
        if (tid == 0) {
            __threadfence();                       // L2 writeback to coherence point
            atomicAdd(&flags[z * 16 + t], 1u);     // release
        }
    } else {
        // ---- PV role ----
        int idx = blockIdx.x - 136;  // 0..127
        int yy = idx >> 3, xx = idx & 7;
        int tm = yy * 128, tn = xx * 128;

        // acquire: wait for all yy+1 scores tiles of row-panel yy (covers P + L)
        if (tid == 0) {
            while (__hip_atomic_load(&flags[z * 16 + yy], __ATOMIC_ACQUIRE,
                                     __HIP_MEMORY_SCOPE_AGENT) < (unsigned)(yy + 1))
                __builtin_amdgcn_s_sleep(4);
        }
        __syncthreads();
        __threadfence();  // invalidate stale cache lines before staging P

        const unsigned short* A  = (z < 2 ? P01 : P23) + (long long)(z & 1) * SS;
        const unsigned short* Bt = VT + (long long)z * sQ;
        float* O = out + (long long)z * sQ;

        f32x16 acc[2][2] = {};
        run_core<SDIM, SDIM>(A, Bt, smem, tm, tn, (tm + 128) / 64, acc);

        const float* Lb = Lrow + (size_t)z * SDIM;
#pragma unroll
        for (int mi = 0; mi < 2; mi++) {
#pragma unroll
            for (int g = 0; g < 4; g++) {
#pragma unroll
                for (int rr = 0; rr < 4; rr++) {
                    int r = tm + wr + mi * 32 + g * 8 + hi * 4 + rr;
                    float inv = 1.0f / Lb[r];
#pragma unroll
                    for (int nj = 0; nj < 2; nj++) {
                        int c = tn + wc + nj * 32 + l31;
                        O[(size_t)r * PDIM + c] = acc[mi][nj][g * 4 + rr] * inv;
                    }
                }
            }
        }
    }
}

// ---------- host ----------
extern "C" void kernel_launch(void* const* d_in, const int* in_sizes, int n_in,
                              void* d_out, int out_size, void* d_ws, size_t ws_size,
                              hipStream_t stream) {
    const float* x  = (const float*)d_in[0];
    const float* Wq = (const float*)d_in[1];
    const float* Wk = (const float*)d_in[2];
    const float* Wv = (const float*)d_in[3];
    float* out = (float*)d_out;

    const size_t MS = (size_t)BDIM * SDIM;        // 8192
    const long long SS = (long long)SDIM * SDIM;  // per-batch score elems
    char* ws = (char*)d_ws;
    size_t off = 0;
    // S01 aliases Xb (Xb dead after QKV GEMM).
    unsigned short* Xb   = (unsigned short*)(ws + off);
    unsigned short* S01  = Xb;                          off += MS * DDIM * 2;           // 16 MB
    unsigned short* WT   = (unsigned short*)(ws + off); off += 3ull * DDIM * PDIM * 2;  // 6 MB
    unsigned short* Q    = (unsigned short*)(ws + off); off += MS * PDIM * 2;           // 16 MB
    unsigned short* Kb   = (unsigned short*)(ws + off); off += MS * PDIM * 2;           // 16 MB
    unsigned short* VT   = (unsigned short*)(ws + off); off += MS * PDIM * 2;           // 16 MB
    unsigned short* S23  = (unsigned short*)(ws + off); off += 2ull * SS * 2;           // 16 MB
    float*          Lrow = (float*)(ws + off);          off += MS * sizeof(float);      // 32 KB
    unsigned int*   flags = (unsigned int*)(ws + off);  off += 64 * sizeof(unsigned);   // 256 B
    // total ~86 MB

    // 1. fused prep: cast x -> bf16 + transpose/cast weights + zero L/flags
    prep_kernel<<<4096 + 768 + 1, 256, 0, stream>>>(x, Wq, Wk, Wv, Xb, WT, Lrow, flags);

    // 2. fused QKV projection -> Q, Kb, VT(transposed)   (1536 blocks)
    qkv_kernel<<<dim3(3 * PDIM / 128, MS / 128, 1), 256, 0, stream>>>(
        Xb, WT, Q, Kb, VT);

    const float alpha = 1.0f / 32.0f;  // 1/sqrt(P)

    // 3. fused tail: scores (544 blocks) + PV (512 blocks), flag handoff
    tail_kernel<<<dim3(136 + 128, 1, BDIM), 256, 0, stream>>>(
        Q, Kb, S01, S23, VT, out, Lrow, flags, alpha);
}

// Round 10
// 222.586 us; speedup vs baseline: 2.1719x; 2.1719x over previous
//
#include <hip/hip_runtime.h>
#include <hip/hip_bf16.h>

// B=4, S=2048, D=1024, P=1024 causal self-attention, bf16 MFMA pipeline.
// Round 17: revert R16's scores+PV flag-handoff merge (352us @ 4% MfmaUtil:
// linear dispatch order left later-z scores blocks non-resident while 512
// PV blocks spun in occupied slots -- inter-block spin handoff refuted).
// Restores R15 (224.6us best) + one isolated micro-opt:
//  - QKV V-transpose epilogue: 2 passes of 64 p-columns (T=64x136 shorts,
//    17.4KB in the dead tile buffer) instead of 4 passes of 32 -> 4 fewer
//    barriers on the 512 V-blocks, same bytes/coalescing.
// Structure: 4 launches: prep(+Lzero), QKV, scores(P0=exp(s-8)+L atomics),
// PV(row-scale 1/L). GEMM core: 128^2 tile, BK=64, 32x32x16 MFMA, 2-barrier
// ktile, chunk-XOR LDS swizzle, PV complementary pairing.

#define BDIM 4
#define SDIM 2048
#define DDIM 1024
#define PDIM 1024

typedef __attribute__((ext_vector_type(8))) short bf16x8;
typedef __attribute__((ext_vector_type(4))) float f32x4;
typedef __attribute__((ext_vector_type(16))) float f32x16;

// ---------- helpers ----------
__device__ __forceinline__ unsigned short f2bf(float f) {
    union { float f; unsigned int u; } v; v.f = f;
    unsigned int u = v.u;
    unsigned int r = (u + 0x7fffu + ((u >> 16) & 1u)) >> 16;
    return (unsigned short)r;
}

__device__ __forceinline__ float bf2f(unsigned short h) {
    union { unsigned int u; float f; } v;
    v.u = ((unsigned int)h) << 16;
    return v.f;
}

__device__ __forceinline__ void async16(const unsigned short* g, unsigned short* l) {
    __builtin_amdgcn_global_load_lds(
        (const __attribute__((address_space(1))) unsigned int*)g,
        (__attribute__((address_space(3))) unsigned int*)l,
        16, 0, 0);
}

// ---------- fused prep: cast x (fp32->bf16) + transpose/cast W + zero L ----------
// x part: 4096 blocks, 32B/thread. W part: 768 blocks, 64x64 transpose tiles.
// Block 4864: zero Lrow (8192 floats).
__global__ __launch_bounds__(256) void prep_kernel(const float* __restrict__ x,
                                                   const float* __restrict__ W0,
                                                   const float* __restrict__ W1,
                                                   const float* __restrict__ W2,
                                                   unsigned short* __restrict__ Xb,
                                                   unsigned short* __restrict__ WT,
                                                   float* __restrict__ Lrow) {
    int bid = blockIdx.x;
    if (bid < 4096) {
        size_t i = (size_t)bid * 256 + threadIdx.x;
        float4 a = ((const float4*)x)[2 * i];
        float4 b = ((const float4*)x)[2 * i + 1];
        bf16x8 o;
        o[0] = (short)f2bf(a.x); o[1] = (short)f2bf(a.y);
        o[2] = (short)f2bf(a.z); o[3] = (short)f2bf(a.w);
        o[4] = (short)f2bf(b.x); o[5] = (short)f2bf(b.y);
        o[6] = (short)f2bf(b.z); o[7] = (short)f2bf(b.w);
        ((bf16x8*)Xb)[i] = o;
    } else if (bid < 4864) {
        int idx = bid - 4096;
        int wz = idx >> 8;   // 0..2
        int t  = idx & 255;
        const float* W = (wz == 0) ? W0 : (wz == 1) ? W1 : W2;
        unsigned short* Tz = WT + (size_t)wz * DDIM * PDIM;
        __shared__ float tle[64 * 65];  // pitch 65: transpose-read is 2-way (free)
        int r0 = (t >> 4) * 64, c0 = (t & 15) * 64;
#pragma unroll
        for (int kk = 0; kk < 4; kk++) {
            int it = (int)threadIdx.x + 256 * kk;
            int r = it >> 4, c4 = (it & 15) * 4;
            float4 v = *(const float4*)(W + (size_t)(r0 + r) * PDIM + c0 + c4);
            float* dst = tle + r * 65 + c4;
            dst[0] = v.x; dst[1] = v.y; dst[2] = v.z; dst[3] = v.w;
        }
        __syncthreads();
#pragma unroll
        for (int kk = 0; kk < 2; kk++) {
            int it = (int)threadIdx.x + 256 * kk;
            int c = it >> 3, ch = (it & 7) * 8;
            bf16x8 o;
#pragma unroll
            for (int j = 0; j < 8; j++)
                o[j] = (short)f2bf(tle[(ch + j) * 65 + c]);
            // WT[n][k] = W[k][n]: n = c0+c, k = r0+ch+j
            *(bf16x8*)(Tz + (size_t)(c0 + c) * DDIM + r0 + ch) = o;
        }
    } else {
        // zero Lrow: 8192 floats = 2048 float4
        float4 z4 = make_float4(0.f, 0.f, 0.f, 0.f);
#pragma unroll
        for (int kk = 0; kk < 8; kk++)
            ((float4*)Lrow)[(size_t)kk * 256 + threadIdx.x] = z4;
    }
}

// ---------- BK=64 GEMM (32x32x16 MFMA): C = A[M][K] @ Bt[N][K]^T ----------
// XOR-swizzled LDS (stored chunk c of row r holds logical chunk c^(r&7)).
// A: ping-pong 2x16 KB; B: single 16 KB buffer (48 KB -> 3 blocks/CU).
// Frag addr: row = wbase + mi*32 + (lane&31); chunk = (ks*2 + lane>>5) ^ (lane&7).
// C/D: col = lane&31, row = (reg&3) + 8*(reg>>2) + 4*(lane>>5)  [guide-verified].
// MODE 0: fused QKV (tn<1024 -> Q, <2048 -> Kb, else VT transposed via LDS).
// MODE 1: causal scores -> P0 = exp(s*alpha - 8) stored bf16 (0 where masked);
//         row sums shfl-reduced and atomicAdd'ed into Lrow[b][r].
// MODE 2: PV, K clamped at tm+BM, output rows scaled by 1/Lrow[b][r];
//         z<2 big-first, z>=2 small-first pairing (CU pair = 17+17 ktiles).
template <int LDA, int LDB, int LDC, int KMAX, int MODE, typename CT>
__global__ __launch_bounds__(256) void gemm_bt(
    const unsigned short* __restrict__ A0, const unsigned short* __restrict__ A1,
    long long sA,
    const unsigned short* __restrict__ B0, long long sB,
    CT* __restrict__ C0, CT* __restrict__ C1, long long sC,
    unsigned short* __restrict__ Kb, unsigned short* __restrict__ VT,
    float* __restrict__ Lrow, float alpha) {
    const int BM = 128, BN = 128, BK = 64;
    const int ABUF = BM * BK;  // 8192 shorts = 16 KB
    __shared__ __attribute__((aligned(16))) unsigned short smem[2 * ABUF + BN * BK];  // 48 KB
    unsigned short* BsBuf = smem + 2 * ABUF;

    int tm, tn;
    if (MODE == 1) {
        int i = blockIdx.x;
        int t = (int)((sqrtf(8.f * i + 1.f) - 1.f) * 0.5f);
        if ((t + 1) * (t + 2) / 2 <= i) t++;
        if (t * (t + 1) / 2 > i) t--;
        tm = t * BM;
        tn = (i - t * (t + 1) / 2) * BN;
    } else if (MODE == 2) {
        int yy = (blockIdx.z < 2) ? ((int)gridDim.y - 1 - (int)blockIdx.y)
                                  : (int)blockIdx.y;
        tm = yy * BM;  // complementary pairing across the z halves
        tn = blockIdx.x * BN;
    } else {
        tm = blockIdx.y * BM;
        tn = blockIdx.x * BN;
    }
    int kend = (MODE == 2) ? min(KMAX, tm + BM) : KMAX;

    int z = blockIdx.z;
    const unsigned short* A = (z < 2 ? A0 : A1) + (long long)(z & 1) * sA;
    const unsigned short* Bt = B0 + (long long)z * sB;
    CT* C = (z < 2 ? C0 : C1) + (long long)(z & 1) * sC;

    int tid  = threadIdx.x;
    int lane = tid & 63;
    int wave = tid >> 6;
    int wr   = (wave >> 1) * 64;   // wave row base (2x2 wave grid, 64x64 out each)
    int wc   = (wave & 1) * 64;
    int l31  = lane & 31;
    int hi   = lane >> 5;
    int rsw  = lane & 7;           // = (LDS row)&7 for frag reads

    f32x16 acc[2][2] = {};         // 2x2 frags of 32x32

    // staging: thread -> (row = tid>>3 (+32/pass), stored chunk = tid&7)
    int srow = tid >> 3;
    int scol = ((tid & 7) ^ (srow & 7)) * 8;
    const unsigned short* Ag = A + (size_t)(tm + srow) * LDA + scol;
    const unsigned short* Bg = Bt + (size_t)(tn + srow) * LDB + scol;

    auto issueA = [&](int k0, int buf) {
        unsigned short* la = smem + buf * ABUF + tid * 8;
        async16(Ag + k0, la);
        async16(Ag + k0 + 32 * LDA, la + 2048);
        async16(Ag + k0 + 64 * LDA, la + 4096);
        async16(Ag + k0 + 96 * LDA, la + 6144);
    };
    auto issueB = [&](int k0) {
        unsigned short* lb = BsBuf + tid * 8;
        async16(Bg + k0, lb);
        async16(Bg + k0 + 32 * LDB, lb + 2048);
        async16(Bg + k0 + 64 * LDB, lb + 4096);
        async16(Bg + k0 + 96 * LDB, lb + 6144);
    };

    auto kbody = [&](int i, int ns) {
        __syncthreads();  // sync1: drains A[i&1] + B (in flight since last iter)
        bf16x8 bf[2][4];
#pragma unroll
        for (int nj = 0; nj < 2; nj++)
#pragma unroll
            for (int ks = 0; ks < 4; ks++)
                bf[nj][ks] = *(const bf16x8*)(BsBuf + (wc + nj * 32 + l31) * BK
                                                    + ((ks * 2 + hi) ^ rsw) * 8);
        __syncthreads();  // sync2: B buffer free (vmcnt already 0 -> cheap)
        if (i + 1 < ns) { issueA((i + 1) * BK, (i + 1) & 1); issueB((i + 1) * BK); }
        const unsigned short* As = smem + (i & 1) * ABUF;
#pragma unroll
        for (int mi = 0; mi < 2; mi++) {
            bf16x8 af[4];
#pragma unroll
            for (int ks = 0; ks < 4; ks++)
                af[ks] = *(const bf16x8*)(As + (wr + mi * 32 + l31) * BK
                                             + ((ks * 2 + hi) ^ rsw) * 8);
#pragma unroll
            for (int ks = 0; ks < 4; ks++)
#pragma unroll
                for (int nj = 0; nj < 2; nj++)
                    acc[mi][nj] = __builtin_amdgcn_mfma_f32_32x32x16_bf16(
                        af[ks], bf[nj][ks], acc[mi][nj], 0, 0, 0);
        }
    };

    issueA(0, 0);
    issueB(0);
    if constexpr (MODE != 2) {
        constexpr int NS = KMAX / BK;
#pragma unroll
        for (int i = 0; i < NS; i++) kbody(i, NS);
    } else {
        int ns = kend / BK;
        for (int i = 0; i < ns; i++) kbody(i, ns);
    }

    // ------ epilogue: col = tn + wc + nj*32 + l31,
    //                  row = tm + wr + mi*32 + 8*g + 4*hi + rr (reg = g*4+rr) ------
    if constexpr (MODE == 0) {
        if (tn < 2048) {
            unsigned short* D = (tn < 1024 ? (unsigned short*)C0 : Kb);
            int cbase = tn & 1023;
#pragma unroll
            for (int mi = 0; mi < 2; mi++) {
#pragma unroll
                for (int nj = 0; nj < 2; nj++) {
                    int c = cbase + wc + nj * 32 + l31;
#pragma unroll
                    for (int g = 0; g < 4; g++) {
                        int r0 = tm + wr + mi * 32 + g * 8 + hi * 4;
#pragma unroll
                        for (int rr = 0; rr < 4; rr++)
                            D[(size_t)(r0 + rr) * 1024 + c] =
                                f2bf(acc[mi][nj][g * 4 + rr]);
                    }
                }
            }
        } else {
            // V region: transposed write via LDS, 2 passes of 64 p-columns.
            // Pass q: waves with wc==64q write T[cl=nj*32+l31][rl], all
            // threads then copy 64 p-rows x 128 s-cols to VT.
            int b = tm >> 11;
            int s0 = tm & 2047;
            unsigned short* VTb = VT + (size_t)b * (PDIM * SDIM)
                                     + (size_t)(tn - 2048) * SDIM + s0;
            const int TP = 136;
            unsigned short* T = smem;  // 64x136 shorts = 17.4 KB, dead tile buffer
            __syncthreads();
#pragma unroll
            for (int q = 0; q < 2; q++) {
                if ((wave & 1) == q) {
#pragma unroll
                    for (int nj = 0; nj < 2; nj++) {
                        int cl = nj * 32 + l31;  // local p-col 0..63
#pragma unroll
                        for (int mi = 0; mi < 2; mi++) {
#pragma unroll
                            for (int g = 0; g < 4; g++) {
                                int rl = wr + mi * 32 + g * 8 + hi * 4;
                                ushort4 w;
                                w.x = f2bf(acc[mi][nj][g * 4 + 0]);
                                w.y = f2bf(acc[mi][nj][g * 4 + 1]);
                                w.z = f2bf(acc[mi][nj][g * 4 + 2]);
                                w.w = f2bf(acc[mi][nj][g * 4 + 3]);
                                *(ushort4*)(T + cl * TP + rl) = w;
                            }
                        }
                    }
                }
                __syncthreads();
                {
                    int lr = tid >> 2;        // p-col 0..63
                    int ck = (tid & 3) * 32;  // s-row chunk 0/32/64/96
                    bf16x8 u0 = *(const bf16x8*)(T + lr * TP + ck);
                    bf16x8 u1 = *(const bf16x8*)(T + lr * TP + ck + 8);
                    bf16x8 u2 = *(const bf16x8*)(T + lr * TP + ck + 16);
                    bf16x8 u3 = *(const bf16x8*)(T + lr * TP + ck + 24);
                    unsigned short* dst = VTb + (size_t)(64 * q + lr) * SDIM + ck;
                    *(bf16x8*)(dst) = u0;
                    *(bf16x8*)(dst + 8) = u1;
                    *(bf16x8*)(dst + 16) = u2;
                    *(bf16x8*)(dst + 24) = u3;
                }
                __syncthreads();
            }
        }
    } else if constexpr (MODE == 1) {
        // P0 = exp(s*alpha - 8), 0 where masked; row-sum -> atomicAdd L[b][r].
        float* Lb = Lrow + (size_t)z * SDIM;
        unsigned short* D = (unsigned short*)C;
#pragma unroll
        for (int mi = 0; mi < 2; mi++) {
#pragma unroll
            for (int g = 0; g < 4; g++) {
#pragma unroll
                for (int rr = 0; rr < 4; rr++) {
                    int r = tm + wr + mi * 32 + g * 8 + hi * 4 + rr;
                    float psum = 0.f;
#pragma unroll
                    for (int nj = 0; nj < 2; nj++) {
                        int c = tn + wc + nj * 32 + l31;
                        float p = 0.f;
                        if (c <= r)
                            p = __expf(acc[mi][nj][g * 4 + rr] * alpha - 8.0f);
                        psum += p;
                        D[(size_t)r * LDC + c] = f2bf(p);
                    }
#pragma unroll
                    for (int o = 16; o; o >>= 1) psum += __shfl_xor(psum, o, 64);
                    if (l31 == 0) atomicAdd(Lb + r, psum);
                }
            }
        }
    } else {
        // PV: scale output rows by 1/L[b][r] (softmax normalization).
        const float* Lb = Lrow + (size_t)z * SDIM;
#pragma unroll
        for (int mi = 0; mi < 2; mi++) {
#pragma unroll
            for (int g = 0; g < 4; g++) {
#pragma unroll
                for (int rr = 0; rr < 4; rr++) {
                    int r = tm + wr + mi * 32 + g * 8 + hi * 4 + rr;
                    float inv = 1.0f / Lb[r];
#pragma unroll
                    for (int nj = 0; nj < 2; nj++) {
                        int c = tn + wc + nj * 32 + l31;
                        C[(size_t)r * LDC + c] = (CT)(acc[mi][nj][g * 4 + rr] * inv);
                    }
                }
            }
        }
    }
}

// ---------- host ----------
extern "C" void kernel_launch(void* const* d_in, const int* in_sizes, int n_in,
                              void* d_out, int out_size, void* d_ws, size_t ws_size,
                              hipStream_t stream) {
    const float* x  = (const float*)d_in[0];
    const float* Wq = (const float*)d_in[1];
    const float* Wk = (const float*)d_in[2];
    const float* Wv = (const float*)d_in[3];
    float* out = (float*)d_out;

    const size_t MS = (size_t)BDIM * SDIM;        // 8192
    const long long SS = (long long)SDIM * SDIM;  // per-batch score elems
    char* ws = (char*)d_ws;
    size_t off = 0;
    // S01 aliases Xb (Xb dead after QKV GEMM).
    unsigned short* Xb   = (unsigned short*)(ws + off);
    unsigned short* S01  = Xb;                          off += MS * DDIM * 2;           // 16 MB
    unsigned short* WT   = (unsigned short*)(ws + off); off += 3ull * DDIM * PDIM * 2;  // 6 MB
    unsigned short* Q    = (unsigned short*)(ws + off); off += MS * PDIM * 2;           // 16 MB
    unsigned short* Kb   = (unsigned short*)(ws + off); off += MS * PDIM * 2;           // 16 MB
    unsigned short* VT   = (unsigned short*)(ws + off); off += MS * PDIM * 2;           // 16 MB
    unsigned short* S23  = (unsigned short*)(ws + off); off += 2ull * SS * 2;           // 16 MB
    float*          Lrow = (float*)(ws + off);          off += MS * sizeof(float);      // 32 KB
    // total ~86 MB

    // 1. fused prep: cast x -> bf16 + transpose/cast weights + zero Lrow
    prep_kernel<<<4096 + 768 + 1, 256, 0, stream>>>(x, Wq, Wk, Wv, Xb, WT, Lrow);

    // 2. fused QKV projection -> Q, Kb, VT(transposed)   (1536 blocks)
    gemm_bt<DDIM, DDIM, PDIM, DDIM, 0, unsigned short>
        <<<dim3(3 * PDIM / 128, MS / 128, 1), 256, 0, stream>>>(
        Xb, Xb, 0, WT, 0, Q, Q, 0, Kb, VT, nullptr, 1.0f);

    const long long sQ = (long long)SDIM * PDIM;   // per-batch Q/K/VT stride
    const float alpha = 1.0f / 32.0f;              // 1/sqrt(P)

    // 3. scores -> P0 = exp(s-8) + row sums L  (136 tiles x 4 batches)
    gemm_bt<PDIM, PDIM, SDIM, PDIM, 1, unsigned short>
        <<<dim3(136, 1, BDIM), 256, 0, stream>>>(
        Q, Q + 2 * sQ, sQ, Kb, sQ, S01, S23, SS, nullptr, nullptr, Lrow, alpha);

    // 4. PV: out_b = (P0_b @ VT_b^T) / L, causal K clamp, complementary pairing
    const long long sOut = (long long)SDIM * PDIM;
    gemm_bt<SDIM, SDIM, PDIM, SDIM, 2, float>
        <<<dim3(PDIM / 128, SDIM / 128, BDIM), 256, 0, stream>>>(
        S01, S23, SS, VT, sQ, out, out + 2 * sOut, sOut, nullptr, nullptr, Lrow, 1.0f);
}